// Round 10
// baseline (82.862 us; speedup 1.0000x reference)
//
#include <hip/hip_runtime.h>
#include <hip/hip_fp16.h>

#define CC 64
#define HH 128
#define WW 128
#define HWS (HH * WW)
#define NG 4

// Fold {grid_sample 2 corners (1-t, t; zeros padding)} x {2x bilinear
// upsample taps, align_corners=False} into <=3 consecutive source taps
// starting at `base`. Branchless, no runtime-indexed locals.
__device__ __forceinline__ void make_taps(float gp, int n, int half, int& base,
                                          float& w0o, float& w1o, float& w2o) {
  float w0 = 0.0f, w1 = 0.0f, w2 = 0.0f;
  float f = floorf(gp);
  int x0 = (int)f;
  float t = gp - f;
  int b = 0;
#pragma unroll
  for (int k = 0; k < 2; ++k) {
    int xc = x0 + k;
    float cw = k ? t : 1.0f - t;
    if (xc < 0 || xc >= n) cw = 0.0f;
    int xcc = min(max(xc, 0), n - 1);
    int u = half * n + xcc;
    float src = fmaxf((float)u * 0.5f - 0.25f, 0.0f);
    float sf = floorf(src);
    int i0 = (int)sf;
    float tu = src - sf;
    int i1 = min(i0 + 1, n - 1);
    if (k == 0) b = i0;
    int s0 = i0 - b;
    int s1 = i1 - b;
    float a0 = cw * (1.0f - tu);
    float a1 = cw * tu;
    w0 += (s0 == 0) ? a0 : 0.0f;
    w1 += (s0 == 1) ? a0 : 0.0f;
    w0 += (s1 == 0) ? a1 : 0.0f;
    w1 += (s1 == 1) ? a1 : 0.0f;
    w2 += (s1 == 2) ? a1 : 0.0f;
  }
  base = b;
  w0o = w0; w1o = w1; w2o = w2;
}

// ---------- Kernel A v3: channel-split prep (unchanged, ~24 us) -------------
__global__ __launch_bounds__(256) void prep_v3(
    const float* __restrict__ x,
    const float* __restrict__ w_off, const float* __restrict__ b_off,
    const float* __restrict__ w_mask, const float* __restrict__ b_mask,
    __half* __restrict__ xT, float* __restrict__ geomC, int npix) {
  __shared__ float wt[CC * 12];
  __shared__ unsigned int tile[64][33];   // packed half2 [px][ch/2], +1 pad
  __shared__ float part[4][64][13];       // conv partials, 13 = 12 + pad
  int t = threadIdx.x;
  for (int idx = t; idx < CC * 12; idx += 256) {
    int c = idx / 12, d = idx - c * 12;
    wt[idx] = (d < 8) ? w_off[d * CC + c] : w_mask[(d - 8) * CC + c];
  }
  __syncthreads();

  int px = t & 63, chq = t >> 6;          // wave = 64 px, same chq
  int pix = blockIdx.x * 64 + px;
  int b = pix >> 14;
  int ij = pix & (HWS - 1);
  const float* __restrict__ xp = x + (size_t)b * CC * HWS + ij;

  // 16 independent coalesced plane loads (256B per wave per instr)
  float xv[16];
#pragma unroll
  for (int k = 0; k < 16; ++k) xv[k] = xp[(size_t)(chq * 16 + k) * HWS];

  float p12[12];
#pragma unroll
  for (int d = 0; d < 12; ++d) p12[d] = 0.0f;
#pragma unroll
  for (int k = 0; k < 16; ++k) {
    int c = chq * 16 + k;
    float v = xv[k];
    const float4 w0 = *reinterpret_cast<const float4*>(&wt[c * 12 + 0]);
    const float4 w1 = *reinterpret_cast<const float4*>(&wt[c * 12 + 4]);
    const float4 w2 = *reinterpret_cast<const float4*>(&wt[c * 12 + 8]);
    p12[0]  = fmaf(w0.x, v, p12[0]);   p12[1]  = fmaf(w0.y, v, p12[1]);
    p12[2]  = fmaf(w0.z, v, p12[2]);   p12[3]  = fmaf(w0.w, v, p12[3]);
    p12[4]  = fmaf(w1.x, v, p12[4]);   p12[5]  = fmaf(w1.y, v, p12[5]);
    p12[6]  = fmaf(w1.z, v, p12[6]);   p12[7]  = fmaf(w1.w, v, p12[7]);
    p12[8]  = fmaf(w2.x, v, p12[8]);   p12[9]  = fmaf(w2.y, v, p12[9]);
    p12[10] = fmaf(w2.z, v, p12[10]);  p12[11] = fmaf(w2.w, v, p12[11]);
  }

  // pack 16 ch -> 8 half2 dwords into tile (bank = (px + c)%32, <=2-way)
#pragma unroll
  for (int k = 0; k < 8; ++k) {
    tile[px][chq * 8 + k] = __builtin_bit_cast(
        unsigned int, __floats2half2_rn(xv[2 * k], xv[2 * k + 1]));
  }
#pragma unroll
  for (int d = 0; d < 12; ++d) part[chq][px][d] = p12[d];
  __syncthreads();

  // coalesced xT store: thread t -> dwords [t*8, t*8+8)
  {
    unsigned int* __restrict__ xtu = reinterpret_cast<unsigned int*>(xT);
    size_t base = (size_t)blockIdx.x * 64 * 32;
    int spx = t >> 2, c0 = (t & 3) * 8;
    uint4 u0, u1;
    u0.x = tile[spx][c0 + 0]; u0.y = tile[spx][c0 + 1];
    u0.z = tile[spx][c0 + 2]; u0.w = tile[spx][c0 + 3];
    u1.x = tile[spx][c0 + 4]; u1.y = tile[spx][c0 + 5];
    u1.z = tile[spx][c0 + 6]; u1.w = tile[spx][c0 + 7];
    *reinterpret_cast<uint4*>(xtu + base + t * 8) = u0;
    *reinterpret_cast<uint4*>(xtu + base + t * 8 + 4) = u1;
  }

  // conv finish + geometry (threads 0..63, one per pixel)
  if (t < 64) {
    int pixg = blockIdx.x * 64 + t;
    int ijg = pixg & (HWS - 1);
    int i = ijg >> 7, j = ijg & (WW - 1);
    float a12[12];
#pragma unroll
    for (int d = 0; d < 12; ++d) {
      a12[d] = ((d < 8) ? b_off[d] : b_mask[d - 8]) + part[0][t][d] +
               part[1][t][d] + part[2][t][d] + part[3][t][d];
    }
    float* __restrict__ gb = geomC + (size_t)(pixg >> 5) * 1024 + (pixg & 31);
#pragma unroll
    for (int g = 0; g < NG; ++g) {
      int sy = g >> 1, sx = g & 1;
      float mg = 1.0f / (1.0f + __expf(-a12[8 + g]));
      int cb, rb;
      float x0, x1, x2, y0, y1, y2;
      make_taps((float)j + a12[2 * g]     - 0.5f, WW, sx, cb, x0, x1, x2);
      make_taps((float)i + a12[2 * g + 1] - 0.5f, HH, sy, rb, y0, y1, y2);
      gb[(g * 8 + 0) * 32] = x0;
      gb[(g * 8 + 1) * 32] = x1;
      gb[(g * 8 + 2) * 32] = x2;
      gb[(g * 8 + 3) * 32] = y0 * mg;
      gb[(g * 8 + 4) * 32] = y1 * mg;
      gb[(g * 8 + 5) * 32] = y2 * mg;
      gb[(g * 8 + 6) * 32] = __int_as_float(rb);
      gb[(g * 8 + 7) * 32] = __int_as_float(cb);
    }
  }
}

// ---------- Kernel B: gather-sampler w/ explicit 9-deep load batching -------
__global__ __launch_bounds__(256) void sample16(
    const __half* __restrict__ xT, const float* __restrict__ geomC,
    float* __restrict__ out, int npix) {
  __shared__ float graw[1024];     // 32 px x 32 dwords, [dword][px]
  __shared__ int2 gexp[32][36];    // expanded (offset, half2 weight) per px
  int t = threadIdx.x;

  int nwg = gridDim.x, bid = blockIdx.x;
  int swz = ((nwg & 7) == 0) ? ((bid & 7) * (nwg >> 3) + (bid >> 3)) : bid;

  reinterpret_cast<uint4*>(graw)[t] =
      reinterpret_cast<const uint4*>(geomC + (size_t)swz * 1024)[t];
  __syncthreads();

  if (t < 128) {  // expand: thread (p,g) -> 9 (off, half2 w) pairs
    int p = t >> 2, g = t & 3;
    float wx0 = graw[(g * 8 + 0) * 32 + p];
    float wx1 = graw[(g * 8 + 1) * 32 + p];
    float wx2 = graw[(g * 8 + 2) * 32 + p];
    float wy0 = graw[(g * 8 + 3) * 32 + p];
    float wy1 = graw[(g * 8 + 4) * 32 + p];
    float wy2 = graw[(g * 8 + 5) * 32 + p];
    int rb = __float_as_int(graw[(g * 8 + 6) * 32 + p]);
    int cb = __float_as_int(graw[(g * 8 + 7) * 32 + p]);
#pragma unroll
    for (int dy = 0; dy < 3; ++dy) {
      int ro = min(rb + dy, HH - 1) * WW;
      float wyv = (dy == 0) ? wy0 : ((dy == 1) ? wy1 : wy2);
#pragma unroll
      for (int dx = 0; dx < 3; ++dx) {
        int off = ro + min(cb + dx, WW - 1);
        float wv = wyv * ((dx == 0) ? wx0 : ((dx == 1) ? wx1 : wx2));
        gexp[p][g * 9 + dy * 3 + dx] =
            make_int2(off, __builtin_bit_cast(int, __float2half2_rn(wv)));
      }
    }
  }
  __syncthreads();

  int p = t >> 3, r = t & 7;       // 8 lanes per pixel, 8 channels per lane
  int pix = swz * 32 + p;
  int b = pix >> 14, ij = pix & (HWS - 1);
  const __half* __restrict__ xb = xT + ((size_t)b * HWS) * 64 + r * 8;

  __half2 acc0 = __float2half2_rn(0.0f);
  __half2 acc1 = acc0, acc2 = acc0, acc3 = acc0;

  // 4 batches of 9 taps: all 9 uint4 loads of a batch are simultaneously
  // live -> compiler must keep ~36 VGPRs of loads in flight (MLP), instead
  // of the 32-VGPR serial chain round 9 produced.
#pragma unroll
  for (int k0 = 0; k0 < 36; k0 += 9) {
    __half2 wh[9];
    int off[9];
#pragma unroll
    for (int k = 0; k < 9; ++k) {
      int2 ow = gexp[p][k0 + k];
      off[k] = ow.x;
      wh[k] = __builtin_bit_cast(__half2, ow.y);
    }
    uint4 v[9];
#pragma unroll
    for (int k = 0; k < 9; ++k) {
      v[k] = *reinterpret_cast<const uint4*>(xb + (size_t)off[k] * 64);
    }
#pragma unroll
    for (int k = 0; k < 9; ++k) {
      acc0 = __hfma2(__builtin_bit_cast(__half2, v[k].x), wh[k], acc0);
      acc1 = __hfma2(__builtin_bit_cast(__half2, v[k].y), wh[k], acc1);
      acc2 = __hfma2(__builtin_bit_cast(__half2, v[k].z), wh[k], acc2);
      acc3 = __hfma2(__builtin_bit_cast(__half2, v[k].w), wh[k], acc3);
    }
  }

  float2 f0 = __half22float2(acc0);
  float2 f1 = __half22float2(acc1);
  float2 f2 = __half22float2(acc2);
  float2 f3 = __half22float2(acc3);
  float* __restrict__ op = out + ((size_t)b * CC + r * 8) * HWS + ij;
  op[0 * HWS] = f0.x;  op[1 * HWS] = f0.y;
  op[2 * HWS] = f1.x;  op[3 * HWS] = f1.y;
  op[4 * HWS] = f2.x;  op[5 * HWS] = f2.y;
  op[6 * HWS] = f3.x;  op[7 * HWS] = f3.y;
}

// ---------- Fallback: round-4 fused kernel (used if ws too small) ----------
__global__ __launch_bounds__(256) void dysample_fused(
    const float* __restrict__ x,
    const float* __restrict__ w_off, const float* __restrict__ b_off,
    const float* __restrict__ w_mask, const float* __restrict__ b_mask,
    float* __restrict__ out, int npix) {
  __shared__ float wt[CC * 12];
  for (int idx = threadIdx.x; idx < CC * 12; idx += 256) {
    int c = idx / 12, d = idx - c * 12;
    wt[idx] = (d < 8) ? w_off[d * CC + c] : w_mask[(d - 8) * CC + c];
  }
  __syncthreads();
  int nwg = gridDim.x;
  int bid = blockIdx.x;
  int swz = ((nwg & 7) == 0) ? ((bid & 7) * (nwg >> 3) + (bid >> 3)) : bid;
  int pix = swz * 256 + threadIdx.x;
  if (pix >= npix) return;
  int b = pix >> 14;
  int ij = pix & (HWS - 1);
  int i = ij >> 7, j = ij & (WW - 1);
  const float* __restrict__ xp = x + (size_t)b * CC * HWS;
  float a12[12];
#pragma unroll
  for (int d = 0; d < 12; ++d) a12[d] = (d < 8) ? b_off[d] : b_mask[d - 8];
#pragma unroll 4
  for (int c = 0; c < CC; ++c) {
    float xv = xp[c * HWS + ij];
    const float4 w0 = *reinterpret_cast<const float4*>(&wt[c * 12 + 0]);
    const float4 w1 = *reinterpret_cast<const float4*>(&wt[c * 12 + 4]);
    const float4 w2 = *reinterpret_cast<const float4*>(&wt[c * 12 + 8]);
    a12[0]  = fmaf(w0.x, xv, a12[0]);   a12[1]  = fmaf(w0.y, xv, a12[1]);
    a12[2]  = fmaf(w0.z, xv, a12[2]);   a12[3]  = fmaf(w0.w, xv, a12[3]);
    a12[4]  = fmaf(w1.x, xv, a12[4]);   a12[5]  = fmaf(w1.y, xv, a12[5]);
    a12[6]  = fmaf(w1.z, xv, a12[6]);   a12[7]  = fmaf(w1.w, xv, a12[7]);
    a12[8]  = fmaf(w2.x, xv, a12[8]);   a12[9]  = fmaf(w2.y, xv, a12[9]);
    a12[10] = fmaf(w2.z, xv, a12[10]);  a12[11] = fmaf(w2.w, xv, a12[11]);
  }
  int ro[NG][3], co[NG][3];
  float wx[NG][3], wy[NG][3];
#pragma unroll
  for (int g = 0; g < NG; ++g) {
    int sy = g >> 1, sx = g & 1;
    float mg = 1.0f / (1.0f + __expf(-a12[8 + g]));
    int cb, rb;
    float x0, x1, x2, y0, y1, y2;
    make_taps((float)j + a12[2 * g]     - 0.5f, WW, sx, cb, x0, x1, x2);
    make_taps((float)i + a12[2 * g + 1] - 0.5f, HH, sy, rb, y0, y1, y2);
    wx[g][0] = x0;      wx[g][1] = x1;      wx[g][2] = x2;
    wy[g][0] = y0 * mg; wy[g][1] = y1 * mg; wy[g][2] = y2 * mg;
#pragma unroll
    for (int d = 0; d < 3; ++d) {
      ro[g][d] = min(rb + d, HH - 1) * WW;
      co[g][d] = min(cb + d, WW - 1);
    }
  }
  float* __restrict__ op = out + (size_t)b * CC * HWS + ij;
  for (int blk = 0; blk < 4; ++blk) {
    const float* __restrict__ xb = xp + blk * 16 * HWS;
    float acc[16];
#pragma unroll
    for (int c = 0; c < 16; ++c) acc[c] = 0.0f;
#pragma unroll
    for (int g = 0; g < NG; ++g) {
      int o9[9];
      float w9[9];
#pragma unroll
      for (int dy = 0; dy < 3; ++dy) {
#pragma unroll
        for (int dx = 0; dx < 3; ++dx) {
          o9[dy * 3 + dx] = ro[g][dy] + co[g][dx];
          w9[dy * 3 + dx] = wy[g][dy] * wx[g][dx];
        }
      }
#pragma unroll
      for (int c = 0; c < 16; ++c) {
        const float* __restrict__ xc = xb + c * HWS;
#pragma unroll
        for (int k = 0; k < 9; ++k) acc[c] = fmaf(w9[k], xc[o9[k]], acc[c]);
      }
    }
#pragma unroll
    for (int c = 0; c < 16; ++c) op[(blk * 16 + c) * HWS] = acc[c];
  }
}

extern "C" void kernel_launch(void* const* d_in, const int* in_sizes, int n_in,
                              void* d_out, int out_size, void* d_ws, size_t ws_size,
                              hipStream_t stream) {
  const float* x      = (const float*)d_in[0];
  const float* w_off  = (const float*)d_in[1];
  const float* b_off  = (const float*)d_in[2];
  const float* w_mask = (const float*)d_in[3];
  const float* b_mask = (const float*)d_in[4];
  float* out = (float*)d_out;

  int B = in_sizes[0] / (CC * HWS);
  int npix = B * HWS;
  // xT (fp16, npix*128 B) + geomC (npix*128 B)
  size_t need = (size_t)npix * 128 + (size_t)npix * 128;

  if (ws_size >= need && (npix & 255) == 0) {
    __half* xT   = (__half*)d_ws;
    float* geomC = (float*)((char*)d_ws + (size_t)npix * 128);
    hipLaunchKernelGGL(prep_v3, dim3(npix / 64), dim3(256), 0, stream,
                       x, w_off, b_off, w_mask, b_mask, xT, geomC, npix);
    hipLaunchKernelGGL(sample16, dim3(npix / 32), dim3(256), 0, stream,
                       xT, geomC, out, npix);
  } else {
    int nblk = (npix + 255) / 256;
    hipLaunchKernelGGL(dysample_fused, dim3(nblk), dim3(256), 0, stream,
                       x, w_off, b_off, w_mask, b_mask, out, npix);
  }
}

// Round 11
// 82.489 us; speedup vs baseline: 1.0045x; 1.0045x over previous
//
#include <hip/hip_runtime.h>
#include <hip/hip_fp16.h>

#define CC 64
#define HH 128
#define WW 128
#define HWS (HH * WW)
#define NG 4

// Fold {grid_sample 2 corners (1-t, t; zeros padding)} x {2x bilinear
// upsample taps, align_corners=False} into <=3 consecutive source taps
// starting at `base`. Branchless, no runtime-indexed locals.
__device__ __forceinline__ void make_taps(float gp, int n, int half, int& base,
                                          float& w0o, float& w1o, float& w2o) {
  float w0 = 0.0f, w1 = 0.0f, w2 = 0.0f;
  float f = floorf(gp);
  int x0 = (int)f;
  float t = gp - f;
  int b = 0;
#pragma unroll
  for (int k = 0; k < 2; ++k) {
    int xc = x0 + k;
    float cw = k ? t : 1.0f - t;
    if (xc < 0 || xc >= n) cw = 0.0f;
    int xcc = min(max(xc, 0), n - 1);
    int u = half * n + xcc;
    float src = fmaxf((float)u * 0.5f - 0.25f, 0.0f);
    float sf = floorf(src);
    int i0 = (int)sf;
    float tu = src - sf;
    int i1 = min(i0 + 1, n - 1);
    if (k == 0) b = i0;
    int s0 = i0 - b;
    int s1 = i1 - b;
    float a0 = cw * (1.0f - tu);
    float a1 = cw * tu;
    w0 += (s0 == 0) ? a0 : 0.0f;
    w1 += (s0 == 1) ? a0 : 0.0f;
    w0 += (s1 == 0) ? a1 : 0.0f;
    w1 += (s1 == 1) ? a1 : 0.0f;
    w2 += (s1 == 2) ? a1 : 0.0f;
  }
  base = b;
  w0o = w0; w1o = w1; w2o = w2;
}

// ---------- Kernel A v3: channel-split prep (unchanged, ~24 us) -------------
__global__ __launch_bounds__(256) void prep_v3(
    const float* __restrict__ x,
    const float* __restrict__ w_off, const float* __restrict__ b_off,
    const float* __restrict__ w_mask, const float* __restrict__ b_mask,
    __half* __restrict__ xT, float* __restrict__ geomC, int npix) {
  __shared__ float wt[CC * 12];
  __shared__ unsigned int tile[64][33];   // packed half2 [px][ch/2], +1 pad
  __shared__ float part[4][64][13];       // conv partials, 13 = 12 + pad
  int t = threadIdx.x;
  for (int idx = t; idx < CC * 12; idx += 256) {
    int c = idx / 12, d = idx - c * 12;
    wt[idx] = (d < 8) ? w_off[d * CC + c] : w_mask[(d - 8) * CC + c];
  }
  __syncthreads();

  int px = t & 63, chq = t >> 6;          // wave = 64 px, same chq
  int pix = blockIdx.x * 64 + px;
  int b = pix >> 14;
  int ij = pix & (HWS - 1);
  const float* __restrict__ xp = x + (size_t)b * CC * HWS + ij;

  // 16 independent coalesced plane loads (256B per wave per instr)
  float xv[16];
#pragma unroll
  for (int k = 0; k < 16; ++k) xv[k] = xp[(size_t)(chq * 16 + k) * HWS];

  float p12[12];
#pragma unroll
  for (int d = 0; d < 12; ++d) p12[d] = 0.0f;
#pragma unroll
  for (int k = 0; k < 16; ++k) {
    int c = chq * 16 + k;
    float v = xv[k];
    const float4 w0 = *reinterpret_cast<const float4*>(&wt[c * 12 + 0]);
    const float4 w1 = *reinterpret_cast<const float4*>(&wt[c * 12 + 4]);
    const float4 w2 = *reinterpret_cast<const float4*>(&wt[c * 12 + 8]);
    p12[0]  = fmaf(w0.x, v, p12[0]);   p12[1]  = fmaf(w0.y, v, p12[1]);
    p12[2]  = fmaf(w0.z, v, p12[2]);   p12[3]  = fmaf(w0.w, v, p12[3]);
    p12[4]  = fmaf(w1.x, v, p12[4]);   p12[5]  = fmaf(w1.y, v, p12[5]);
    p12[6]  = fmaf(w1.z, v, p12[6]);   p12[7]  = fmaf(w1.w, v, p12[7]);
    p12[8]  = fmaf(w2.x, v, p12[8]);   p12[9]  = fmaf(w2.y, v, p12[9]);
    p12[10] = fmaf(w2.z, v, p12[10]);  p12[11] = fmaf(w2.w, v, p12[11]);
  }

  // pack 16 ch -> 8 half2 dwords into tile (bank = (px + c)%32, <=2-way)
#pragma unroll
  for (int k = 0; k < 8; ++k) {
    tile[px][chq * 8 + k] = __builtin_bit_cast(
        unsigned int, __floats2half2_rn(xv[2 * k], xv[2 * k + 1]));
  }
#pragma unroll
  for (int d = 0; d < 12; ++d) part[chq][px][d] = p12[d];
  __syncthreads();

  // coalesced xT store: thread t -> dwords [t*8, t*8+8)
  {
    unsigned int* __restrict__ xtu = reinterpret_cast<unsigned int*>(xT);
    size_t base = (size_t)blockIdx.x * 64 * 32;
    int spx = t >> 2, c0 = (t & 3) * 8;
    uint4 u0, u1;
    u0.x = tile[spx][c0 + 0]; u0.y = tile[spx][c0 + 1];
    u0.z = tile[spx][c0 + 2]; u0.w = tile[spx][c0 + 3];
    u1.x = tile[spx][c0 + 4]; u1.y = tile[spx][c0 + 5];
    u1.z = tile[spx][c0 + 6]; u1.w = tile[spx][c0 + 7];
    *reinterpret_cast<uint4*>(xtu + base + t * 8) = u0;
    *reinterpret_cast<uint4*>(xtu + base + t * 8 + 4) = u1;
  }

  // conv finish + geometry (threads 0..63, one per pixel)
  if (t < 64) {
    int pixg = blockIdx.x * 64 + t;
    int ijg = pixg & (HWS - 1);
    int i = ijg >> 7, j = ijg & (WW - 1);
    float a12[12];
#pragma unroll
    for (int d = 0; d < 12; ++d) {
      a12[d] = ((d < 8) ? b_off[d] : b_mask[d - 8]) + part[0][t][d] +
               part[1][t][d] + part[2][t][d] + part[3][t][d];
    }
    float* __restrict__ gb = geomC + (size_t)(pixg >> 5) * 1024 + (pixg & 31);
#pragma unroll
    for (int g = 0; g < NG; ++g) {
      int sy = g >> 1, sx = g & 1;
      float mg = 1.0f / (1.0f + __expf(-a12[8 + g]));
      int cb, rb;
      float x0, x1, x2, y0, y1, y2;
      make_taps((float)j + a12[2 * g]     - 0.5f, WW, sx, cb, x0, x1, x2);
      make_taps((float)i + a12[2 * g + 1] - 0.5f, HH, sy, rb, y0, y1, y2);
      gb[(g * 8 + 0) * 32] = x0;
      gb[(g * 8 + 1) * 32] = x1;
      gb[(g * 8 + 2) * 32] = x2;
      gb[(g * 8 + 3) * 32] = y0 * mg;
      gb[(g * 8 + 4) * 32] = y1 * mg;
      gb[(g * 8 + 5) * 32] = y2 * mg;
      gb[(g * 8 + 6) * 32] = __int_as_float(rb);
      gb[(g * 8 + 7) * 32] = __int_as_float(cb);
    }
  }
}

// ---------- Kernel B: gather-sampler w/ asm-fenced 9-deep MLP ---------------
__global__ __launch_bounds__(256) void sample16(
    const __half* __restrict__ xT, const float* __restrict__ geomC,
    float* __restrict__ out, int npix) {
  __shared__ float graw[1024];     // 32 px x 32 dwords, [dword][px]
  __shared__ int2 gexp[32][36];    // expanded (offset, half2 weight) per px
  int t = threadIdx.x;

  int nwg = gridDim.x, bid = blockIdx.x;
  int swz = ((nwg & 7) == 0) ? ((bid & 7) * (nwg >> 3) + (bid >> 3)) : bid;

  reinterpret_cast<uint4*>(graw)[t] =
      reinterpret_cast<const uint4*>(geomC + (size_t)swz * 1024)[t];
  __syncthreads();

  if (t < 128) {  // expand: thread (p,g) -> 9 (off, half2 w) pairs
    int p = t >> 2, g = t & 3;
    float wx0 = graw[(g * 8 + 0) * 32 + p];
    float wx1 = graw[(g * 8 + 1) * 32 + p];
    float wx2 = graw[(g * 8 + 2) * 32 + p];
    float wy0 = graw[(g * 8 + 3) * 32 + p];
    float wy1 = graw[(g * 8 + 4) * 32 + p];
    float wy2 = graw[(g * 8 + 5) * 32 + p];
    int rb = __float_as_int(graw[(g * 8 + 6) * 32 + p]);
    int cb = __float_as_int(graw[(g * 8 + 7) * 32 + p]);
#pragma unroll
    for (int dy = 0; dy < 3; ++dy) {
      int ro = min(rb + dy, HH - 1) * WW;
      float wyv = (dy == 0) ? wy0 : ((dy == 1) ? wy1 : wy2);
#pragma unroll
      for (int dx = 0; dx < 3; ++dx) {
        int off = ro + min(cb + dx, WW - 1);
        float wv = wyv * ((dx == 0) ? wx0 : ((dx == 1) ? wx1 : wx2));
        gexp[p][g * 9 + dy * 3 + dx] =
            make_int2(off, __builtin_bit_cast(int, __float2half2_rn(wv)));
      }
    }
  }
  __syncthreads();

  int p = t >> 3, r = t & 7;       // 8 lanes per pixel, 8 channels per lane
  int pix = swz * 32 + p;
  int b = pix >> 14, ij = pix & (HWS - 1);
  const __half* __restrict__ xb = xT + ((size_t)b * HWS) * 64 + r * 8;

  __half2 acc0 = __float2half2_rn(0.0f);
  __half2 acc1 = acc0, acc2 = acc0, acc3 = acc0;

  // 4 batches of 9 taps. The empty asm consumes one dword of EVERY load
  // result, so all 9 loads must complete before it -> the compiler has to
  // issue the 9 loads back-to-back (one s_waitcnt), giving 9 outstanding
  // VMEM ops per wave instead of the serial load->wait->fma chain it
  // produced in rounds 9/10 (VGPR stuck at 32 = ~1-2 in flight).
#pragma unroll
  for (int k0 = 0; k0 < 36; k0 += 9) {
    __half2 wh[9];
    int off[9];
#pragma unroll
    for (int k = 0; k < 9; ++k) {
      int2 ow = gexp[p][k0 + k];
      off[k] = ow.x;
      wh[k] = __builtin_bit_cast(__half2, ow.y);
    }
    uint4 v[9];
#pragma unroll
    for (int k = 0; k < 9; ++k) {
      v[k] = *reinterpret_cast<const uint4*>(xb + (size_t)off[k] * 64);
    }
    asm volatile("" ::
        "v"(v[0].x), "v"(v[1].x), "v"(v[2].x),
        "v"(v[3].x), "v"(v[4].x), "v"(v[5].x),
        "v"(v[6].x), "v"(v[7].x), "v"(v[8].x));
#pragma unroll
    for (int k = 0; k < 9; ++k) {
      acc0 = __hfma2(__builtin_bit_cast(__half2, v[k].x), wh[k], acc0);
      acc1 = __hfma2(__builtin_bit_cast(__half2, v[k].y), wh[k], acc1);
      acc2 = __hfma2(__builtin_bit_cast(__half2, v[k].z), wh[k], acc2);
      acc3 = __hfma2(__builtin_bit_cast(__half2, v[k].w), wh[k], acc3);
    }
  }

  float2 f0 = __half22float2(acc0);
  float2 f1 = __half22float2(acc1);
  float2 f2 = __half22float2(acc2);
  float2 f3 = __half22float2(acc3);
  float* __restrict__ op = out + ((size_t)b * CC + r * 8) * HWS + ij;
  op[0 * HWS] = f0.x;  op[1 * HWS] = f0.y;
  op[2 * HWS] = f1.x;  op[3 * HWS] = f1.y;
  op[4 * HWS] = f2.x;  op[5 * HWS] = f2.y;
  op[6 * HWS] = f3.x;  op[7 * HWS] = f3.y;
}

// ---------- Fallback: round-4 fused kernel (used if ws too small) ----------
__global__ __launch_bounds__(256) void dysample_fused(
    const float* __restrict__ x,
    const float* __restrict__ w_off, const float* __restrict__ b_off,
    const float* __restrict__ w_mask, const float* __restrict__ b_mask,
    float* __restrict__ out, int npix) {
  __shared__ float wt[CC * 12];
  for (int idx = threadIdx.x; idx < CC * 12; idx += 256) {
    int c = idx / 12, d = idx - c * 12;
    wt[idx] = (d < 8) ? w_off[d * CC + c] : w_mask[(d - 8) * CC + c];
  }
  __syncthreads();
  int nwg = gridDim.x;
  int bid = blockIdx.x;
  int swz = ((nwg & 7) == 0) ? ((bid & 7) * (nwg >> 3) + (bid >> 3)) : bid;
  int pix = swz * 256 + threadIdx.x;
  if (pix >= npix) return;
  int b = pix >> 14;
  int ij = pix & (HWS - 1);
  int i = ij >> 7, j = ij & (WW - 1);
  const float* __restrict__ xp = x + (size_t)b * CC * HWS;
  float a12[12];
#pragma unroll
  for (int d = 0; d < 12; ++d) a12[d] = (d < 8) ? b_off[d] : b_mask[d - 8];
#pragma unroll 4
  for (int c = 0; c < CC; ++c) {
    float xv = xp[c * HWS + ij];
    const float4 w0 = *reinterpret_cast<const float4*>(&wt[c * 12 + 0]);
    const float4 w1 = *reinterpret_cast<const float4*>(&wt[c * 12 + 4]);
    const float4 w2 = *reinterpret_cast<const float4*>(&wt[c * 12 + 8]);
    a12[0]  = fmaf(w0.x, xv, a12[0]);   a12[1]  = fmaf(w0.y, xv, a12[1]);
    a12[2]  = fmaf(w0.z, xv, a12[2]);   a12[3]  = fmaf(w0.w, xv, a12[3]);
    a12[4]  = fmaf(w1.x, xv, a12[4]);   a12[5]  = fmaf(w1.y, xv, a12[5]);
    a12[6]  = fmaf(w1.z, xv, a12[6]);   a12[7]  = fmaf(w1.w, xv, a12[7]);
    a12[8]  = fmaf(w2.x, xv, a12[8]);   a12[9]  = fmaf(w2.y, xv, a12[9]);
    a12[10] = fmaf(w2.z, xv, a12[10]);  a12[11] = fmaf(w2.w, xv, a12[11]);
  }
  int ro[NG][3], co[NG][3];
  float wx[NG][3], wy[NG][3];
#pragma unroll
  for (int g = 0; g < NG; ++g) {
    int sy = g >> 1, sx = g & 1;
    float mg = 1.0f / (1.0f + __expf(-a12[8 + g]));
    int cb, rb;
    float x0, x1, x2, y0, y1, y2;
    make_taps((float)j + a12[2 * g]     - 0.5f, WW, sx, cb, x0, x1, x2);
    make_taps((float)i + a12[2 * g + 1] - 0.5f, HH, sy, rb, y0, y1, y2);
    wx[g][0] = x0;      wx[g][1] = x1;      wx[g][2] = x2;
    wy[g][0] = y0 * mg; wy[g][1] = y1 * mg; wy[g][2] = y2 * mg;
#pragma unroll
    for (int d = 0; d < 3; ++d) {
      ro[g][d] = min(rb + d, HH - 1) * WW;
      co[g][d] = min(cb + d, WW - 1);
    }
  }
  float* __restrict__ op = out + (size_t)b * CC * HWS + ij;
  for (int blk = 0; blk < 4; ++blk) {
    const float* __restrict__ xb = xp + blk * 16 * HWS;
    float acc[16];
#pragma unroll
    for (int c = 0; c < 16; ++c) acc[c] = 0.0f;
#pragma unroll
    for (int g = 0; g < NG; ++g) {
      int o9[9];
      float w9[9];
#pragma unroll
      for (int dy = 0; dy < 3; ++dy) {
#pragma unroll
        for (int dx = 0; dx < 3; ++dx) {
          o9[dy * 3 + dx] = ro[g][dy] + co[g][dx];
          w9[dy * 3 + dx] = wy[g][dy] * wx[g][dx];
        }
      }
#pragma unroll
      for (int c = 0; c < 16; ++c) {
        const float* __restrict__ xc = xb + c * HWS;
#pragma unroll
        for (int k = 0; k < 9; ++k) acc[c] = fmaf(w9[k], xc[o9[k]], acc[c]);
      }
    }
#pragma unroll
    for (int c = 0; c < 16; ++c) op[(blk * 16 + c) * HWS] = acc[c];
  }
}

extern "C" void kernel_launch(void* const* d_in, const int* in_sizes, int n_in,
                              void* d_out, int out_size, void* d_ws, size_t ws_size,
                              hipStream_t stream) {
  const float* x      = (const float*)d_in[0];
  const float* w_off  = (const float*)d_in[1];
  const float* b_off  = (const float*)d_in[2];
  const float* w_mask = (const float*)d_in[3];
  const float* b_mask = (const float*)d_in[4];
  float* out = (float*)d_out;

  int B = in_sizes[0] / (CC * HWS);
  int npix = B * HWS;
  // xT (fp16, npix*128 B) + geomC (npix*128 B)
  size_t need = (size_t)npix * 128 + (size_t)npix * 128;

  if (ws_size >= need && (npix & 255) == 0) {
    __half* xT   = (__half*)d_ws;
    float* geomC = (float*)((char*)d_ws + (size_t)npix * 128);
    hipLaunchKernelGGL(prep_v3, dim3(npix / 64), dim3(256), 0, stream,
                       x, w_off, b_off, w_mask, b_mask, xT, geomC, npix);
    hipLaunchKernelGGL(sample16, dim3(npix / 32), dim3(256), 0, stream,
                       xT, geomC, out, npix);
  } else {
    int nblk = (npix + 255) / 256;
    hipLaunchKernelGGL(dysample_fused, dim3(nblk), dim3(256), 0, stream,
                       x, w_off, b_off, w_mask, b_mask, out, npix);
  }
}